// Round 4
// baseline (578.726 us; speedup 1.0000x reference)
//
#include <hip/hip_runtime.h>
#include <hip/hip_bf16.h>

#define B_ 16
#define C_ 256
#define N_ 4096

// log2(10000)/128
#define THK (13.287712379549449f / 128.f)

typedef float f4 __attribute__((ext_vector_type(4)));
typedef short s8 __attribute__((ext_vector_type(8)));
typedef unsigned short us8 __attribute__((ext_vector_type(8)));

__device__ __forceinline__ float bf2f(unsigned short u) {
    unsigned int ui = ((unsigned int)u) << 16;
    return __uint_as_float(ui);
}
__device__ __forceinline__ unsigned short f2bf(float f) {
    unsigned int ui = __float_as_uint(f);
    ui += 0x7fffu + ((ui >> 16) & 1u);
    return (unsigned short)(ui >> 16);
}

// ---------------------------------------------------------------------------
// K1: 4 depthwise convs (k=3,5,7,9) from one LDS x-tile; block-uniform scalar
//     weight loads; fully unrolled so the compiler hoists s_loads.
// grid (2 htiles, 256 c, 16 b), block 256. Tile: 40 rows x 76-pitch.
// ---------------------------------------------------------------------------
__global__ __launch_bounds__(256) void k1_conv_stats(
    const float* __restrict__ x,
    const float* __restrict__ cw3, const float* __restrict__ cb3,
    const float* __restrict__ cw5, const float* __restrict__ cb5,
    const float* __restrict__ cw7, const float* __restrict__ cb7,
    const float* __restrict__ cw9, const float* __restrict__ cb9,
    unsigned short* __restrict__ y,   // [4][B][C][N] bf16
    float* __restrict__ stats)        // [4][B][4][2]
{
    __shared__ float tile[40 * 76];
    __shared__ float red[4][8];
    const int t = threadIdx.x;
    const int h0 = blockIdx.x * 32;
    const int c  = blockIdx.y;
    const int b  = blockIdx.z;

    const float* xc = x + (size_t)(b * C_ + c) * N_;
    for (int i = 0; i < 12; ++i) {
        int flat = i * 256 + t;
        if (flat < 40 * 76) {
            int r = flat / 76, col = flat % 76;
            int h = h0 - 4 + r, w = col - 4;
            float v = 0.f;
            if ((unsigned)h < 64u && (unsigned)w < 64u && col < 72) v = xc[h * 64 + w];
            tile[flat] = v;
        }
    }
    __syncthreads();

    const int w8 = (t & 7) * 8;
    const int hr = t >> 3;
    float a3[8], a5[8], a7[8], a9[8];
    #pragma unroll
    for (int j = 0; j < 8; ++j) { a3[j]=0.f; a5[j]=0.f; a7[j]=0.f; a9[j]=0.f; }

    const float* w9p = cw9 + c * 81;
    const float* w7p = cw7 + c * 49;
    const float* w5p = cw5 + c * 25;
    const float* w3p = cw3 + c * 9;

    #pragma unroll
    for (int r9 = 0; r9 < 9; ++r9) {
        const float* xr = &tile[(hr + r9) * 76 + w8];
        float xv[16];
        #pragma unroll
        for (int q = 0; q < 4; ++q) {
            f4 tv = *(const f4*)(xr + q * 4);
            xv[q*4+0] = tv[0]; xv[q*4+1] = tv[1]; xv[q*4+2] = tv[2]; xv[q*4+3] = tv[3];
        }
        #pragma unroll
        for (int dx = 0; dx < 9; ++dx) {
            float wv = w9p[r9 * 9 + dx];
            #pragma unroll
            for (int j = 0; j < 8; ++j) a9[j] = fmaf(wv, xv[j + dx], a9[j]);
        }
        int r7 = r9 - 1;
        if ((unsigned)r7 < 7u) {
            #pragma unroll
            for (int dx = 0; dx < 7; ++dx) {
                float wv = w7p[r7 * 7 + dx];
                #pragma unroll
                for (int j = 0; j < 8; ++j) a7[j] = fmaf(wv, xv[j + dx + 1], a7[j]);
            }
        }
        int r5 = r9 - 2;
        if ((unsigned)r5 < 5u) {
            #pragma unroll
            for (int dx = 0; dx < 5; ++dx) {
                float wv = w5p[r5 * 5 + dx];
                #pragma unroll
                for (int j = 0; j < 8; ++j) a5[j] = fmaf(wv, xv[j + dx + 2], a5[j]);
            }
        }
        int r3 = r9 - 3;
        if ((unsigned)r3 < 3u) {
            #pragma unroll
            for (int dx = 0; dx < 3; ++dx) {
                float wv = w3p[r3 * 3 + dx];
                #pragma unroll
                for (int j = 0; j < 8; ++j) a3[j] = fmaf(wv, xv[j + dx + 3], a3[j]);
            }
        }
    }

    float bb0 = cb3[c], bb1 = cb5[c], bb2 = cb7[c], bb3 = cb9[c];
    float s[4], ss[4];
    const size_t L = (size_t)B_ * C_ * N_;
    size_t ybase = (size_t)(b * C_ + c) * N_ + (size_t)(h0 + hr) * 64 + w8;

    #pragma unroll
    for (int l = 0; l < 4; ++l) {
        float bias = (l == 0) ? bb0 : (l == 1) ? bb1 : (l == 2) ? bb2 : bb3;
        float* ap = (l == 0) ? a3 : (l == 1) ? a5 : (l == 2) ? a7 : a9;
        float s1 = 0.f, s2 = 0.f;
        us8 pk;
        #pragma unroll
        for (int j = 0; j < 8; ++j) {
            float v = ap[j] + bias;
            pk[j] = f2bf(v);
            s1 += v; s2 += v * v;
        }
        *reinterpret_cast<us8*>(y + (size_t)l * L + ybase) = pk;
        s[l] = s1; ss[l] = s2;
    }

    #pragma unroll
    for (int l = 0; l < 4; ++l) {
        float aa = s[l], qq = ss[l];
        for (int off = 1; off < 64; off <<= 1) { aa += __shfl_xor(aa, off); qq += __shfl_xor(qq, off); }
        s[l] = aa; ss[l] = qq;
    }
    const int lane = t & 63, wvi = t >> 6;
    if (lane == 0) {
        #pragma unroll
        for (int l = 0; l < 4; ++l) { red[wvi][l*2] = s[l]; red[wvi][l*2+1] = ss[l]; }
    }
    __syncthreads();
    if (t < 8) {
        float tot = red[0][t] + red[1][t] + red[2][t] + red[3][t];
        int l = t >> 1, which = t & 1, g = c >> 6;
        atomicAdd(&stats[((l * 16 + b) * 4 + g) * 2 + which], tot);
    }
}

// ---------------------------------------------------------------------------
// K2: groupnorm + sigmoid + softmax fusion; write vT bf16 [b,c,n] and
//     xs bf16 [b,n,c] (LDS transpose).
// grid (64 ntiles, 4 groups, 16 b), block 256
// ---------------------------------------------------------------------------
__global__ __launch_bounds__(256) void k2_fuse(
    const unsigned short* __restrict__ y, const float* __restrict__ stats,
    const float* __restrict__ gnw, const float* __restrict__ gnb,
    const float* __restrict__ fw,
    unsigned short* __restrict__ xs, unsigned short* __restrict__ vT)
{
    __shared__ float tile[64 * 65];
    const int t = threadIdx.x;
    const int n0 = blockIdx.x * 64;
    const int cg = blockIdx.y;
    const int b  = blockIdx.z;
    const int c0 = cg * 64;

    float f0 = fw[0], f1 = fw[1], f2 = fw[2], f3 = fw[3];
    float mx = fmaxf(fmaxf(f0, f1), fmaxf(f2, f3));
    float e0 = __expf(f0 - mx), e1 = __expf(f1 - mx), e2 = __expf(f2 - mx), e3 = __expf(f3 - mx);
    float inv = 1.f / (e0 + e1 + e2 + e3);
    float wts[4] = { e0 * inv, e1 * inv, e2 * inv, e3 * inv };

    float mean[4], rstd[4];
    const float invN = 1.0f / 262144.0f;
    #pragma unroll
    for (int l = 0; l < 4; ++l) {
        float s1 = stats[((l * 16 + b) * 4 + cg) * 2 + 0];
        float s2 = stats[((l * 16 + b) * 4 + cg) * 2 + 1];
        float m = s1 * invN;
        float var = fmaxf(s2 * invN - m * m, 0.f);
        mean[l] = m; rstd[l] = rsqrtf(var + 1e-5f);
    }
    const size_t L = (size_t)B_ * C_ * N_;
    for (int i = 0; i < 16; ++i) {
        int ci = i * 4 + (t >> 6);
        int nj = t & 63;
        int c = c0 + ci;
        size_t base = (size_t)(b * C_ + c) * N_ + n0 + nj;
        float acc = 0.f;
        #pragma unroll
        for (int l = 0; l < 4; ++l) {
            float yv = bf2f(y[(size_t)l * L + base]);
            float g = (yv - mean[l]) * rstd[l] * gnw[l * 256 + c] + gnb[l * 256 + c];
            acc += wts[l] * (1.0f / (1.0f + __expf(-g)));
        }
        vT[base] = f2bf(acc);
        tile[ci * 65 + nj] = acc;
    }
    __syncthreads();
    for (int i = 0; i < 16; ++i) {
        int nj = i * 4 + (t >> 6);
        int ci = t & 63;
        xs[((size_t)b * N_ + n0 + nj) * C_ + c0 + ci] = f2bf(tile[ci * 65 + nj]);
    }
}

__global__ __launch_bounds__(256) void k2b_cvt(const float* __restrict__ w,
                                              unsigned short* __restrict__ o, int n)
{
    int i = blockIdx.x * 256 + threadIdx.x;
    if (i < n) o[i] = f2bf(w[i]);
}

// ---------------------------------------------------------------------------
// K3: qk GEMM (bf16 MFMA) with fused elu+1, RoPE, kmean.
//     Outputs: q_rope bf16 [b,n,c], k_ropeT bf16 [b,c,n].
// grid (256, 8), block 256 (4 waves, each 64 tokens x 64 channels)
// ---------------------------------------------------------------------------
__global__ __launch_bounds__(256) void k3_gemm(
    const short* __restrict__ A, const short* __restrict__ Bw,
    unsigned short* __restrict__ q_rope, unsigned short* __restrict__ k_ropeT,
    float* __restrict__ kmean)
{
    __shared__ float stage[4 * 32 * 65];
    const int t = threadIdx.x, lane = t & 63, wv = t >> 6;
    const int m0 = blockIdx.x * 256 + wv * 64;   // global token base of wave
    const int n0 = blockIdx.y * 64;              // channel base (0..511)
    const int mr = lane & 15, koff = (lane >> 4) * 8;
    const int quad = lane >> 4, rbase = quad * 4;

    f4 acc[4][4];
    #pragma unroll
    for (int a = 0; a < 4; ++a)
        #pragma unroll
        for (int bn = 0; bn < 4; ++bn) { acc[a][bn][0]=0.f; acc[a][bn][1]=0.f; acc[a][bn][2]=0.f; acc[a][bn][3]=0.f; }

    for (int k0 = 0; k0 < 256; k0 += 32) {
        s8 af[4], bfr[4];
        #pragma unroll
        for (int mt = 0; mt < 4; ++mt)
            af[mt] = *(const s8*)(A + (size_t)(m0 + mt * 16 + mr) * 256 + k0 + koff);
        #pragma unroll
        for (int nt = 0; nt < 4; ++nt)
            bfr[nt] = *(const s8*)(Bw + (size_t)(n0 + nt * 16 + mr) * 256 + k0 + koff);
        #pragma unroll
        for (int mt = 0; mt < 4; ++mt)
            #pragma unroll
            for (int nt = 0; nt < 4; ++nt)
                acc[mt][nt] = __builtin_amdgcn_mfma_f32_16x16x32_bf16(af[mt], bfr[nt], acc[mt][nt], 0, 0, 0);
    }

    const int b = blockIdx.x >> 4;
    const int tokb = m0 & 4095;
    float* sw = stage + wv * (32 * 65);
    float ksum = 0.f;

    for (int half = 0; half < 2; ++half) {
        #pragma unroll
        for (int mt2 = 0; mt2 < 2; ++mt2) {
            int mt = half * 2 + mt2;
            #pragma unroll
            for (int nt = 0; nt < 4; ++nt)
                #pragma unroll
                for (int r = 0; r < 4; ++r) {
                    float v = acc[mt][nt][r];
                    v = v > 0.f ? v + 1.f : __expf(v);   // elu+1
                    sw[(mt2 * 16 + rbase + r) * 65 + nt * 16 + mr] = v;
                }
        }
        __syncthreads();
        if (n0 < 256) {
            // q half: lane>>1 = token row (0..31), lane&1 = 32-channel half
            int row = lane >> 1;
            int choff = (lane & 1) * 32;
            int gtok = m0 + half * 32 + row;
            float wpos = (float)(gtok & 63);
            unsigned short obuf[32];
            #pragma unroll
            for (int j = 0; j < 16; ++j) {
                int ch = n0 + choff + 2 * j;
                float theta = exp2f(-(float)(ch >> 1) * THK);
                float ang = wpos * theta;
                float sv, cv; sincosf(ang, &sv, &cv);
                float xx = sw[row * 65 + choff + 2 * j];
                float yy = sw[row * 65 + choff + 2 * j + 1];
                obuf[2*j]   = f2bf(cv * xx - sv * yy);
                obuf[2*j+1] = f2bf(sv * xx + cv * yy);
            }
            unsigned short* dst = q_rope + (size_t)gtok * 256 + n0 + choff;
            #pragma unroll
            for (int u = 0; u < 4; ++u)
                *(us8*)(dst + u * 8) = *(const us8*)(obuf + u * 8);
        } else {
            // k half: lane = channel col; read LDS column (stride 65, conflict-free)
            int ch = (n0 - 256) + lane;
            float theta = exp2f(-(float)(ch >> 1) * THK);
            unsigned short obuf[32];
            #pragma unroll
            for (int i = 0; i < 32; ++i) {
                float val = sw[i * 65 + lane];
                ksum += val;
                float pv = __shfl_xor(val, 1);
                float ang = (float)((tokb + half * 32 + i) & 63) * theta;
                float sv, cv; sincosf(ang, &sv, &cv);
                obuf[i] = f2bf((ch & 1) ? (sv * pv + cv * val) : (cv * val - sv * pv));
            }
            unsigned short* dst = k_ropeT + (size_t)(b * 256 + ch) * 4096 + tokb + half * 32;
            #pragma unroll
            for (int u = 0; u < 4; ++u)
                *(us8*)(dst + u * 8) = *(const us8*)(obuf + u * 8);
        }
        __syncthreads();
    }
    if (n0 >= 256) {
        int ch = (n0 - 256) + lane;
        atomicAdd(&kmean[b * 256 + ch], ksum * (1.0f / 4096.0f));
    }
}

// ---------------------------------------------------------------------------
// K5: kv[d,e] = (1/n) sum_n k_rope[n,d] v[n,e] via bf16 MFMA, split-K,
//     LDS reduce across 4 waves, fp32 atomics.
// grid (16 splits, 4 h, 16 b), block 256
// ---------------------------------------------------------------------------
__global__ __launch_bounds__(256) void k5_kv(
    const unsigned short* __restrict__ kT, const unsigned short* __restrict__ vT,
    float* __restrict__ kv)
{
    __shared__ float red[4 * 4096];
    const int t = threadIdx.x, lane = t & 63, wv = t >> 6;
    const int mr = lane & 15, koff = (lane >> 4) * 8, quad = lane >> 4;
    const int s = blockIdx.x, h = blockIdx.y, b = blockIdx.z;
    const int tok0 = s * 256 + wv * 64;

    const unsigned short* Ab = kT + (size_t)(b * 256 + h * 64) * 4096 + tok0;
    const unsigned short* Bb = vT + (size_t)(b * 256 + h * 64) * 4096 + tok0;

    f4 acc[4][4];
    #pragma unroll
    for (int a = 0; a < 4; ++a)
        #pragma unroll
        for (int bn = 0; bn < 4; ++bn) { acc[a][bn][0]=0.f; acc[a][bn][1]=0.f; acc[a][bn][2]=0.f; acc[a][bn][3]=0.f; }

    #pragma unroll
    for (int ks = 0; ks < 2; ++ks) {
        s8 af[4], bfr[4];
        #pragma unroll
        for (int mt = 0; mt < 4; ++mt)
            af[mt] = *(const s8*)(Ab + (size_t)(mt * 16 + mr) * 4096 + ks * 32 + koff);
        #pragma unroll
        for (int nt = 0; nt < 4; ++nt)
            bfr[nt] = *(const s8*)(Bb + (size_t)(nt * 16 + mr) * 4096 + ks * 32 + koff);
        #pragma unroll
        for (int mt = 0; mt < 4; ++mt)
            #pragma unroll
            for (int nt = 0; nt < 4; ++nt)
                acc[mt][nt] = __builtin_amdgcn_mfma_f32_16x16x32_bf16(af[mt], bfr[nt], acc[mt][nt], 0, 0, 0);
    }

    float* rw = red + wv * 4096;
    #pragma unroll
    for (int mt = 0; mt < 4; ++mt)
        #pragma unroll
        for (int nt = 0; nt < 4; ++nt)
            #pragma unroll
            for (int r = 0; r < 4; ++r)
                rw[(mt * 16 + quad * 4 + r) * 64 + nt * 16 + mr] = acc[mt][nt][r];
    __syncthreads();

    float* kvp = kv + (size_t)(b * 4 + h) * 4096;
    for (int i = 0; i < 16; ++i) {
        int idx = i * 256 + t;
        float s4 = red[idx] + red[4096 + idx] + red[8192 + idx] + red[12288 + idx];
        atomicAdd(&kvp[idx], s4 * (1.0f / 4096.0f));
    }
}

// ---------------------------------------------------------------------------
// K6: attn = (q_rope @ kv) * z via bf16 MFMA; z via rotated-kmean trick;
//     epilogue LDS transpose to write d_out [b,c,n].
// grid (16 ntiles, 4 h, 16 b), block 256
// ---------------------------------------------------------------------------
__global__ __launch_bounds__(256) void k6_attn(
    const unsigned short* __restrict__ q_rope, const float* __restrict__ kmean,
    const float* __restrict__ kv, float* __restrict__ out)
{
    __shared__ unsigned short kvB[64 * 64];  // [e][d] bf16
    __shared__ float zl[256];
    __shared__ float kml[64];
    __shared__ float trans[4][32 * 65];
    const int t = threadIdx.x, lane = t & 63, wv = t >> 6;
    const int mr = lane & 15, koff = (lane >> 4) * 8, quad = lane >> 4;
    const int ntb = blockIdx.x, h = blockIdx.y, b = blockIdx.z;
    const int n0 = ntb * 256;

    // build kv^T bf16 in LDS
    {
        const float* kvp = kv + (size_t)(b * 4 + h) * 4096;
        int e = t >> 2, dseg = (t & 3) * 16;
        unsigned short tmp[16];
        #pragma unroll
        for (int i = 0; i < 16; ++i) tmp[i] = f2bf(kvp[(dseg + i) * 64 + e]);
        *(us8*)&kvB[e * 64 + dseg]     = *(const us8*)tmp;
        *(us8*)&kvB[e * 64 + dseg + 8] = *(const us8*)(tmp + 8);
    }
    if (t < 64) kml[t] = kmean[b * 256 + h * 64 + t];
    __syncthreads();

    // z per token: z = 1/(q_rope . R(ang) kmean + 1e-6)
    {
        const unsigned short* qp = q_rope + (size_t)(b * 4096 + n0 + t) * 256 + h * 64;
        float q[64];
        #pragma unroll
        for (int u = 0; u < 8; ++u) {
            us8 v = *(const us8*)(qp + u * 8);
            #pragma unroll
            for (int j = 0; j < 8; ++j) q[u * 8 + j] = bf2f(v[j]);
        }
        float wpos = (float)((n0 + t) & 63);
        float den = 0.f;
        #pragma unroll
        for (int j = 0; j < 32; ++j) {
            float theta = exp2f(-(float)(h * 32 + j) * THK);
            float ang = wpos * theta;
            float sv, cv; sincosf(ang, &sv, &cv);
            float kmx = kml[2 * j], kmy = kml[2 * j + 1];
            den += q[2 * j] * (cv * kmx - sv * kmy) + q[2 * j + 1] * (sv * kmx + cv * kmy);
        }
        zl[t] = 1.0f / (den + 1e-6f);
    }
    __syncthreads();

    // B fragments from LDS
    s8 bfr[4][2];
    #pragma unroll
    for (int nt = 0; nt < 4; ++nt)
        #pragma unroll
        for (int ks = 0; ks < 2; ++ks)
            bfr[nt][ks] = *(const s8*)&kvB[(nt * 16 + mr) * 64 + ks * 32 + koff];

    const unsigned short* Ab = q_rope + (size_t)(b * 4096 + n0 + wv * 64) * 256 + h * 64;
    f4 acc[4][4];
    #pragma unroll
    for (int a = 0; a < 4; ++a)
        #pragma unroll
        for (int bn = 0; bn < 4; ++bn) { acc[a][bn][0]=0.f; acc[a][bn][1]=0.f; acc[a][bn][2]=0.f; acc[a][bn][3]=0.f; }

    #pragma unroll
    for (int ks = 0; ks < 2; ++ks) {
        s8 af[4];
        #pragma unroll
        for (int mt = 0; mt < 4; ++mt)
            af[mt] = *(const s8*)(Ab + (size_t)(mt * 16 + mr) * 256 + ks * 32 + koff);
        #pragma unroll
        for (int mt = 0; mt < 4; ++mt)
            #pragma unroll
            for (int nt = 0; nt < 4; ++nt)
                acc[mt][nt] = __builtin_amdgcn_mfma_f32_16x16x32_bf16(af[mt], bfr[nt][ks], acc[mt][nt], 0, 0, 0);
    }

    // epilogue: scale by z, transpose 32 tokens at a time, write [c][n]
    float* sw = trans[wv];
    for (int half = 0; half < 2; ++half) {
        #pragma unroll
        for (int mt2 = 0; mt2 < 2; ++mt2) {
            #pragma unroll
            for (int r = 0; r < 4; ++r) {
                int row_rel = mt2 * 16 + quad * 4 + r;
                float z = zl[wv * 64 + half * 32 + row_rel];
                #pragma unroll
                for (int nt = 0; nt < 4; ++nt)
                    sw[row_rel * 65 + nt * 16 + mr] = acc[half * 2 + mt2][nt][r] * z;
            }
        }
        __syncthreads();
        float tmp[32];
        #pragma unroll
        for (int i = 0; i < 32; ++i) tmp[i] = sw[i * 65 + lane];
        float* orow = out + (size_t)(b * 256 + h * 64 + lane) * 4096 + n0 + wv * 64 + half * 32;
        #pragma unroll
        for (int u = 0; u < 8; ++u)
            *(f4*)(orow + u * 4) = *(const f4*)(tmp + u * 4);
        __syncthreads();
    }
}

// ---------------------------------------------------------------------------
// K7: LePE 3x3 depthwise conv on v (bf16 [b,c,n]) + bias, RMW-add into d_out.
// grid (256 c, 16 b), block 256
// ---------------------------------------------------------------------------
__global__ __launch_bounds__(256) void k7_lepe(
    const unsigned short* __restrict__ vT, const float* __restrict__ lw,
    const float* __restrict__ lb, float* __restrict__ out)
{
    __shared__ float tile[66 * 68];
    const int t = threadIdx.x;
    const int c = blockIdx.x, b = blockIdx.y;
    const unsigned short* fc = vT + (size_t)(b * C_ + c) * N_;
    for (int i = 0; i < 18; ++i) {
        int flat = i * 256 + t;
        if (flat < 66 * 68) {
            int r = flat / 68, col = flat % 68;
            int h = r - 1, w = col - 1;
            float v = 0.f;
            if ((unsigned)h < 64u && (unsigned)w < 64u) v = bf2f(fc[h * 64 + w]);
            tile[r * 68 + col] = v;
        }
    }
    __syncthreads();
    float w00 = lw[c*9+0], w01 = lw[c*9+1], w02 = lw[c*9+2];
    float w10 = lw[c*9+3], w11 = lw[c*9+4], w12 = lw[c*9+5];
    float w20 = lw[c*9+6], w21 = lw[c*9+7], w22 = lw[c*9+8];
    float bias = lb[c];
    const int w4 = (t & 15) * 4;
    float* oc = out + (size_t)(b * C_ + c) * N_;
    for (int hh = 0; hh < 4; ++hh) {
        int h = (t >> 4) + hh * 16;
        float r0[6], r1[6], r2[6];
        #pragma unroll
        for (int u = 0; u < 6; ++u) {
            r0[u] = tile[(h + 0) * 68 + w4 + u];
            r1[u] = tile[(h + 1) * 68 + w4 + u];
            r2[u] = tile[(h + 2) * 68 + w4 + u];
        }
        f4 prev = *(const f4*)&oc[h * 64 + w4];
        #pragma unroll
        for (int j = 0; j < 4; ++j) {
            float o = bias;
            o = fmaf(w00, r0[j],   o); o = fmaf(w01, r0[j+1], o); o = fmaf(w02, r0[j+2], o);
            o = fmaf(w10, r1[j],   o); o = fmaf(w11, r1[j+1], o); o = fmaf(w12, r1[j+2], o);
            o = fmaf(w20, r2[j],   o); o = fmaf(w21, r2[j+1], o); o = fmaf(w22, r2[j+2], o);
            prev[j] += o;
        }
        *(f4*)&oc[h * 64 + w4] = prev;
    }
}

// ---------------------------------------------------------------------------
extern "C" void kernel_launch(void* const* d_in, const int* in_sizes, int n_in,
                              void* d_out, int out_size, void* d_ws, size_t ws_size,
                              hipStream_t stream)
{
    const float* x   = (const float*)d_in[0];
    const float* w3  = (const float*)d_in[1];  const float* b3 = (const float*)d_in[2];
    const float* w5  = (const float*)d_in[3];  const float* b5 = (const float*)d_in[4];
    const float* w7  = (const float*)d_in[5];  const float* b7 = (const float*)d_in[6];
    const float* w9  = (const float*)d_in[7];  const float* b9 = (const float*)d_in[8];
    const float* gnw = (const float*)d_in[9];  const float* gnb = (const float*)d_in[10];
    const float* fw  = (const float*)d_in[11];
    const float* qkw = (const float*)d_in[12];
    const float* lw  = (const float*)d_in[13]; const float* lb = (const float*)d_in[14];

    char* ws = (char*)d_ws;
    // layout (bytes):
    //   [0, 128MiB)     y bf16 [4][B][C][N]  -- ALIASED later by q_rope (0..32M)
    //                   and k_ropeT (32M..64M); y dead after k2.
    //   [128M, 160M)    xs bf16 [B][N][C]
    //   [160M, 192M)    vT bf16 [B][C][N]
    //   [192M, +256K)   qk_w bf16
    //   then stats (2KB) | kmean (16KB) | kv fp32 (1MB)  -- one memset
    unsigned short* y      = (unsigned short*)(ws + 0);
    unsigned short* q_rope = (unsigned short*)(ws + 0);
    unsigned short* kT     = (unsigned short*)(ws + 33554432ull);
    unsigned short* xs     = (unsigned short*)(ws + 134217728ull);
    unsigned short* vT     = (unsigned short*)(ws + 167772160ull);
    unsigned short* wb     = (unsigned short*)(ws + 201326592ull);
    float*          stats  = (float*)(ws + 201588736ull);
    float*          kmean  = (float*)(ws + 201590784ull);
    float*          kv     = (float*)(ws + 201607168ull);

    (void)hipMemsetAsync(stats, 0, 2048 + 16384 + 1048576, stream);

    k1_conv_stats<<<dim3(2, 256, 16), 256, 0, stream>>>(x, w3, b3, w5, b5, w7, b7, w9, b9, y, stats);
    k2b_cvt<<<dim3(512), 256, 0, stream>>>(qkw, wb, 131072);
    k2_fuse<<<dim3(64, 4, 16), 256, 0, stream>>>(y, stats, gnw, gnb, fw, xs, vT);
    k3_gemm<<<dim3(256, 8), 256, 0, stream>>>((const short*)xs, (const short*)wb, q_rope, kT, kmean);
    k5_kv<<<dim3(16, 4, 16), 256, 0, stream>>>(kT, vT, kv);
    k6_attn<<<dim3(16, 4, 16), 256, 0, stream>>>(q_rope, kmean, kv, (float*)d_out);
    k7_lepe<<<dim3(256, 16), 256, 0, stream>>>(vT, lw, lb, (float*)d_out);
}

// Round 5
// 461.821 us; speedup vs baseline: 1.2531x; 1.2531x over previous
//
#include <hip/hip_runtime.h>
#include <hip/hip_bf16.h>

#define B_ 16
#define C_ 256
#define N_ 4096

// log2(10000)/128
#define THK (13.287712379549449f / 128.f)

typedef float f4 __attribute__((ext_vector_type(4)));
typedef float f2 __attribute__((ext_vector_type(2)));
typedef short s8 __attribute__((ext_vector_type(8)));
typedef unsigned short us8 __attribute__((ext_vector_type(8)));

__device__ __forceinline__ float bf2f(unsigned short u) {
    unsigned int ui = ((unsigned int)u) << 16;
    return __uint_as_float(ui);
}
__device__ __forceinline__ unsigned short f2bf(float f) {
    unsigned int ui = __float_as_uint(f);
    ui += 0x7fffu + ((ui >> 16) & 1u);
    return (unsigned short)(ui >> 16);
}

// ---------------------------------------------------------------------------
// K0: RoPE table  ropeT[w*128+jj] = (cos(w*theta_jj), sin(w*theta_jj))
// ---------------------------------------------------------------------------
__global__ __launch_bounds__(256) void k0_rope(float* __restrict__ ropeT)
{
    int idx = blockIdx.x * 256 + threadIdx.x;   // 8192
    int w = idx >> 7, jj = idx & 127;
    float theta = exp2f(-(float)jj * THK);
    float sv, cv; sincosf((float)w * theta, &sv, &cv);
    ropeT[idx * 2] = cv; ropeT[idx * 2 + 1] = sv;
}

// ---------------------------------------------------------------------------
// K1: 4 depthwise convs (k=3,5,7,9) from one LDS x-tile; block-uniform scalar
//     weight loads; fully unrolled.
// grid (2 htiles, 256 c, 16 b), block 256. Tile: 40 rows x 76-pitch.
// ---------------------------------------------------------------------------
__global__ __launch_bounds__(256) void k1_conv_stats(
    const float* __restrict__ x,
    const float* __restrict__ cw3, const float* __restrict__ cb3,
    const float* __restrict__ cw5, const float* __restrict__ cb5,
    const float* __restrict__ cw7, const float* __restrict__ cb7,
    const float* __restrict__ cw9, const float* __restrict__ cb9,
    unsigned short* __restrict__ y,   // [4][B][C][N] bf16
    float* __restrict__ stats)        // [4][B][4][2]
{
    __shared__ float tile[40 * 76];
    __shared__ float red[4][8];
    const int t = threadIdx.x;
    const int h0 = blockIdx.x * 32;
    const int c  = blockIdx.y;
    const int b  = blockIdx.z;

    const float* xc = x + (size_t)(b * C_ + c) * N_;
    for (int i = 0; i < 12; ++i) {
        int flat = i * 256 + t;
        if (flat < 40 * 76) {
            int r = flat / 76, col = flat % 76;
            int h = h0 - 4 + r, w = col - 4;
            float v = 0.f;
            if ((unsigned)h < 64u && (unsigned)w < 64u && col < 72) v = xc[h * 64 + w];
            tile[flat] = v;
        }
    }
    __syncthreads();

    const int w8 = (t & 7) * 8;
    const int hr = t >> 3;
    float a3[8], a5[8], a7[8], a9[8];
    #pragma unroll
    for (int j = 0; j < 8; ++j) { a3[j]=0.f; a5[j]=0.f; a7[j]=0.f; a9[j]=0.f; }

    const float* w9p = cw9 + c * 81;
    const float* w7p = cw7 + c * 49;
    const float* w5p = cw5 + c * 25;
    const float* w3p = cw3 + c * 9;

    #pragma unroll
    for (int r9 = 0; r9 < 9; ++r9) {
        const float* xr = &tile[(hr + r9) * 76 + w8];
        float xv[16];
        #pragma unroll
        for (int q = 0; q < 4; ++q) {
            f4 tv = *(const f4*)(xr + q * 4);
            xv[q*4+0] = tv[0]; xv[q*4+1] = tv[1]; xv[q*4+2] = tv[2]; xv[q*4+3] = tv[3];
        }
        #pragma unroll
        for (int dx = 0; dx < 9; ++dx) {
            float wv = w9p[r9 * 9 + dx];
            #pragma unroll
            for (int j = 0; j < 8; ++j) a9[j] = fmaf(wv, xv[j + dx], a9[j]);
        }
        int r7 = r9 - 1;
        if ((unsigned)r7 < 7u) {
            #pragma unroll
            for (int dx = 0; dx < 7; ++dx) {
                float wv = w7p[r7 * 7 + dx];
                #pragma unroll
                for (int j = 0; j < 8; ++j) a7[j] = fmaf(wv, xv[j + dx + 1], a7[j]);
            }
        }
        int r5 = r9 - 2;
        if ((unsigned)r5 < 5u) {
            #pragma unroll
            for (int dx = 0; dx < 5; ++dx) {
                float wv = w5p[r5 * 5 + dx];
                #pragma unroll
                for (int j = 0; j < 8; ++j) a5[j] = fmaf(wv, xv[j + dx + 2], a5[j]);
            }
        }
        int r3 = r9 - 3;
        if ((unsigned)r3 < 3u) {
            #pragma unroll
            for (int dx = 0; dx < 3; ++dx) {
                float wv = w3p[r3 * 3 + dx];
                #pragma unroll
                for (int j = 0; j < 8; ++j) a3[j] = fmaf(wv, xv[j + dx + 3], a3[j]);
            }
        }
    }

    float bb0 = cb3[c], bb1 = cb5[c], bb2 = cb7[c], bb3 = cb9[c];
    float s[4], ss[4];
    const size_t L = (size_t)B_ * C_ * N_;
    size_t ybase = (size_t)(b * C_ + c) * N_ + (size_t)(h0 + hr) * 64 + w8;

    #pragma unroll
    for (int l = 0; l < 4; ++l) {
        float bias = (l == 0) ? bb0 : (l == 1) ? bb1 : (l == 2) ? bb2 : bb3;
        float* ap = (l == 0) ? a3 : (l == 1) ? a5 : (l == 2) ? a7 : a9;
        float s1 = 0.f, s2 = 0.f;
        us8 pk;
        #pragma unroll
        for (int j = 0; j < 8; ++j) {
            float v = ap[j] + bias;
            pk[j] = f2bf(v);
            s1 += v; s2 += v * v;
        }
        *reinterpret_cast<us8*>(y + (size_t)l * L + ybase) = pk;
        s[l] = s1; ss[l] = s2;
    }

    #pragma unroll
    for (int l = 0; l < 4; ++l) {
        float aa = s[l], qq = ss[l];
        for (int off = 1; off < 64; off <<= 1) { aa += __shfl_xor(aa, off); qq += __shfl_xor(qq, off); }
        s[l] = aa; ss[l] = qq;
    }
    const int lane = t & 63, wvi = t >> 6;
    if (lane == 0) {
        #pragma unroll
        for (int l = 0; l < 4; ++l) { red[wvi][l*2] = s[l]; red[wvi][l*2+1] = ss[l]; }
    }
    __syncthreads();
    if (t < 8) {
        float tot = red[0][t] + red[1][t] + red[2][t] + red[3][t];
        int l = t >> 1, which = t & 1, g = c >> 6;
        atomicAdd(&stats[((l * 16 + b) * 4 + g) * 2 + which], tot);
    }
}

// ---------------------------------------------------------------------------
// K2: groupnorm + sigmoid + softmax fusion; write vT bf16 [b,c,n] and
//     xs bf16 [b,n,c] (LDS transpose).
// grid (64 ntiles, 4 groups, 16 b), block 256
// ---------------------------------------------------------------------------
__global__ __launch_bounds__(256) void k2_fuse(
    const unsigned short* __restrict__ y, const float* __restrict__ stats,
    const float* __restrict__ gnw, const float* __restrict__ gnb,
    const float* __restrict__ fw,
    unsigned short* __restrict__ xs, unsigned short* __restrict__ vT)
{
    __shared__ float tile[64 * 65];
    const int t = threadIdx.x;
    const int n0 = blockIdx.x * 64;
    const int cg = blockIdx.y;
    const int b  = blockIdx.z;
    const int c0 = cg * 64;

    float f0 = fw[0], f1 = fw[1], f2 = fw[2], f3 = fw[3];
    float mx = fmaxf(fmaxf(f0, f1), fmaxf(f2, f3));
    float e0 = __expf(f0 - mx), e1 = __expf(f1 - mx), e2 = __expf(f2 - mx), e3 = __expf(f3 - mx);
    float inv = 1.f / (e0 + e1 + e2 + e3);
    float wts[4] = { e0 * inv, e1 * inv, e2 * inv, e3 * inv };

    float mean[4], rstd[4];
    const float invN = 1.0f / 262144.0f;
    #pragma unroll
    for (int l = 0; l < 4; ++l) {
        float s1 = stats[((l * 16 + b) * 4 + cg) * 2 + 0];
        float s2 = stats[((l * 16 + b) * 4 + cg) * 2 + 1];
        float m = s1 * invN;
        float var = fmaxf(s2 * invN - m * m, 0.f);
        mean[l] = m; rstd[l] = rsqrtf(var + 1e-5f);
    }
    const size_t L = (size_t)B_ * C_ * N_;
    for (int i = 0; i < 16; ++i) {
        int ci = i * 4 + (t >> 6);
        int nj = t & 63;
        int c = c0 + ci;
        size_t base = (size_t)(b * C_ + c) * N_ + n0 + nj;
        float acc = 0.f;
        #pragma unroll
        for (int l = 0; l < 4; ++l) {
            float yv = bf2f(y[(size_t)l * L + base]);
            float g = (yv - mean[l]) * rstd[l] * gnw[l * 256 + c] + gnb[l * 256 + c];
            acc += wts[l] * (1.0f / (1.0f + __expf(-g)));
        }
        vT[base] = f2bf(acc);
        tile[ci * 65 + nj] = acc;
    }
    __syncthreads();
    for (int i = 0; i < 16; ++i) {
        int nj = i * 4 + (t >> 6);
        int ci = t & 63;
        xs[((size_t)b * N_ + n0 + nj) * C_ + c0 + ci] = f2bf(tile[ci * 65 + nj]);
    }
}

__global__ __launch_bounds__(256) void k2b_cvt(const float* __restrict__ w,
                                              unsigned short* __restrict__ o, int n)
{
    int i = blockIdx.x * 256 + threadIdx.x;
    if (i < n) o[i] = f2bf(w[i]);
}

// ---------------------------------------------------------------------------
// K3: qk GEMM (bf16 MFMA). Block = 64 tokens x ALL 512 outputs (A staged in
//     LDS once). Waves 0,1 = q-half (RoPE in registers, table); waves 2,3 =
//     k-half (per-wave LDS transpose + RoPE + kmean).
// grid (1024), block 256
// ---------------------------------------------------------------------------
__global__ __launch_bounds__(256, 2) void k3_gemm(
    const short* __restrict__ A, const short* __restrict__ Bw,
    const float* __restrict__ ropeT,
    unsigned short* __restrict__ q_rope, unsigned short* __restrict__ k_ropeT,
    float* __restrict__ kmean)
{
    __shared__ short Atile[64 * 264];       // pitch 264 shorts (pad 8) = 33 KB
    __shared__ float kst[2][32 * 132];      // k-wave transpose stage, 33.8 KB
    const int t = threadIdx.x, lane = t & 63, wv = t >> 6;
    const int m0 = blockIdx.x * 64;         // global token base (b*4096 + tok)
    const int b = m0 >> 12;
    const int tokb = m0 & 4095;
    const int mr = lane & 15, koff = (lane >> 4) * 8, quad = lane >> 4;
    const int n0w = wv * 128;               // output channel base of this wave

    // stage A tile [64 tok][256 k] -> LDS (padded rows)
    {
        const short* src = A + (size_t)m0 * 256;
        #pragma unroll
        for (int i = 0; i < 8; ++i) {
            int flat = i * 2048 + t * 8;
            int row = flat >> 8, col = flat & 255;
            *(s8*)(Atile + row * 264 + col) = *(const s8*)(src + flat);
        }
    }
    __syncthreads();

    f4 acc[4][8];
    #pragma unroll
    for (int a = 0; a < 4; ++a)
        #pragma unroll
        for (int bn = 0; bn < 8; ++bn) { acc[a][bn][0]=0.f; acc[a][bn][1]=0.f; acc[a][bn][2]=0.f; acc[a][bn][3]=0.f; }

    #pragma unroll
    for (int ks = 0; ks < 8; ++ks) {
        const int k0 = ks * 32;
        s8 af[4], bfr[8];
        #pragma unroll
        for (int mt = 0; mt < 4; ++mt)
            af[mt] = *(const s8*)(Atile + (mt * 16 + mr) * 264 + k0 + koff);
        #pragma unroll
        for (int nt = 0; nt < 8; ++nt)
            bfr[nt] = *(const s8*)(Bw + (size_t)(n0w + nt * 16 + mr) * 256 + k0 + koff);
        #pragma unroll
        for (int mt = 0; mt < 4; ++mt)
            #pragma unroll
            for (int nt = 0; nt < 8; ++nt)
                acc[mt][nt] = __builtin_amdgcn_mfma_f32_16x16x32_bf16(af[mt], bfr[nt], acc[mt][nt], 0, 0, 0);
    }

    if (wv < 2) {
        // ---- q half: RoPE in registers, direct b16 stores ----
        #pragma unroll
        for (int mt = 0; mt < 4; ++mt) {
            #pragma unroll
            for (int r = 0; r < 4; ++r) {
                int tok = m0 + mt * 16 + quad * 4 + r;
                int w = tok & 63;
                unsigned short* orow = q_rope + (size_t)tok * 256;
                #pragma unroll
                for (int nt = 0; nt < 8; ++nt) {
                    int ch = n0w + nt * 16 + mr;
                    float v = acc[mt][nt][r];
                    v = v > 0.f ? v + 1.f : __expf(v);
                    float pv = __shfl_xor(v, 1);
                    int jj = ch >> 1;
                    f2 cs = *(const f2*)(ropeT + (w * 128 + jj) * 2);
                    float o = (ch & 1) ? cs[1] * pv + cs[0] * v : cs[0] * v - cs[1] * pv;
                    orow[ch] = f2bf(o);
                }
            }
        }
    } else {
        // ---- k half: per-wave LDS transpose + RoPE + kmean ----
        float* sw = kst[wv - 2];
        float ksum[2] = {0.f, 0.f};
        for (int half = 0; half < 2; ++half) {
            #pragma unroll
            for (int mt2 = 0; mt2 < 2; ++mt2) {
                int mt = half * 2 + mt2;
                #pragma unroll
                for (int nt = 0; nt < 8; ++nt)
                    #pragma unroll
                    for (int r = 0; r < 4; ++r) {
                        float v = acc[mt][nt][r];
                        v = v > 0.f ? v + 1.f : __expf(v);
                        sw[(mt2 * 16 + quad * 4 + r) * 132 + nt * 16 + mr] = v;
                    }
            }
            // same-wave RAW through LDS: ordered by waitcnt, no barrier needed
            #pragma unroll
            for (int cc = 0; cc < 2; ++cc) {
                int col = cc * 64 + lane;
                int kidx = (wv - 2) * 128 + col;      // 0..255
                int jj = kidx >> 1;
                unsigned short obuf[32];
                float ks = 0.f;
                #pragma unroll
                for (int i = 0; i < 32; ++i) {
                    float v = sw[i * 132 + col];
                    ks += v;
                    float pv = __shfl_xor(v, 1);
                    int w = (tokb + half * 32 + i) & 63;
                    f2 cs = *(const f2*)(ropeT + (w * 128 + jj) * 2);
                    obuf[i] = f2bf((kidx & 1) ? cs[1] * pv + cs[0] * v : cs[0] * v - cs[1] * pv);
                }
                unsigned short* dst = k_ropeT + (size_t)(b * 256 + kidx) * 4096 + tokb + half * 32;
                #pragma unroll
                for (int u = 0; u < 4; ++u)
                    *(us8*)(dst + u * 8) = *(const us8*)(obuf + u * 8);
                ksum[cc] += ks;
            }
        }
        atomicAdd(&kmean[b * 256 + (wv - 2) * 128 + lane], ksum[0] * (1.0f / 4096.0f));
        atomicAdd(&kmean[b * 256 + (wv - 2) * 128 + 64 + lane], ksum[1] * (1.0f / 4096.0f));
    }
}

// ---------------------------------------------------------------------------
// K5: kv[d,e] = (1/n) sum_n k_rope[n,d] v[n,e] via bf16 MFMA, split-K,
//     LDS reduce across 4 waves, fp32 atomics.
// grid (16 splits, 4 h, 16 b), block 256
// ---------------------------------------------------------------------------
__global__ __launch_bounds__(256) void k5_kv(
    const unsigned short* __restrict__ kT, const unsigned short* __restrict__ vT,
    float* __restrict__ kv)
{
    __shared__ float red[4 * 4096];
    const int t = threadIdx.x, lane = t & 63, wv = t >> 6;
    const int mr = lane & 15, koff = (lane >> 4) * 8, quad = lane >> 4;
    const int s = blockIdx.x, h = blockIdx.y, b = blockIdx.z;
    const int tok0 = s * 256 + wv * 64;

    const unsigned short* Ab = kT + (size_t)(b * 256 + h * 64) * 4096 + tok0;
    const unsigned short* Bb = vT + (size_t)(b * 256 + h * 64) * 4096 + tok0;

    f4 acc[4][4];
    #pragma unroll
    for (int a = 0; a < 4; ++a)
        #pragma unroll
        for (int bn = 0; bn < 4; ++bn) { acc[a][bn][0]=0.f; acc[a][bn][1]=0.f; acc[a][bn][2]=0.f; acc[a][bn][3]=0.f; }

    #pragma unroll
    for (int ks = 0; ks < 2; ++ks) {
        s8 af[4], bfr[4];
        #pragma unroll
        for (int mt = 0; mt < 4; ++mt)
            af[mt] = *(const s8*)(Ab + (size_t)(mt * 16 + mr) * 4096 + ks * 32 + koff);
        #pragma unroll
        for (int nt = 0; nt < 4; ++nt)
            bfr[nt] = *(const s8*)(Bb + (size_t)(nt * 16 + mr) * 4096 + ks * 32 + koff);
        #pragma unroll
        for (int mt = 0; mt < 4; ++mt)
            #pragma unroll
            for (int nt = 0; nt < 4; ++nt)
                acc[mt][nt] = __builtin_amdgcn_mfma_f32_16x16x32_bf16(af[mt], bfr[nt], acc[mt][nt], 0, 0, 0);
    }

    float* rw = red + wv * 4096;
    #pragma unroll
    for (int mt = 0; mt < 4; ++mt)
        #pragma unroll
        for (int nt = 0; nt < 4; ++nt)
            #pragma unroll
            for (int r = 0; r < 4; ++r)
                rw[(mt * 16 + quad * 4 + r) * 64 + nt * 16 + mr] = acc[mt][nt][r];
    __syncthreads();

    float* kvp = kv + (size_t)(b * 4 + h) * 4096;
    for (int i = 0; i < 16; ++i) {
        int idx = i * 256 + t;
        float s4 = red[idx] + red[4096 + idx] + red[8192 + idx] + red[12288 + idx];
        atomicAdd(&kvp[idx], s4 * (1.0f / 4096.0f));
    }
}

// ---------------------------------------------------------------------------
// K6: attn = (q_rope @ kv) * z via bf16 MFMA; z via rotated-kmean (table);
//     epilogue LDS transpose to write d_out [b,c,n].
// grid (16 ntiles, 4 h, 16 b), block 256
// ---------------------------------------------------------------------------
__global__ __launch_bounds__(256) void k6_attn(
    const unsigned short* __restrict__ q_rope, const float* __restrict__ kmean,
    const float* __restrict__ kv, const float* __restrict__ ropeT,
    float* __restrict__ out)
{
    __shared__ unsigned short kvB[64 * 64];
    __shared__ float zl[256];
    __shared__ float kml[64];
    __shared__ float trans[4][32 * 65];
    const int t = threadIdx.x, lane = t & 63, wv = t >> 6;
    const int mr = lane & 15, koff = (lane >> 4) * 8, quad = lane >> 4;
    const int ntb = blockIdx.x, h = blockIdx.y, b = blockIdx.z;
    const int n0 = ntb * 256;

    {
        const float* kvp = kv + (size_t)(b * 4 + h) * 4096;
        int e = t >> 2, dseg = (t & 3) * 16;
        unsigned short tmp[16];
        #pragma unroll
        for (int i = 0; i < 16; ++i) tmp[i] = f2bf(kvp[(dseg + i) * 64 + e]);
        *(us8*)&kvB[e * 64 + dseg]     = *(const us8*)tmp;
        *(us8*)&kvB[e * 64 + dseg + 8] = *(const us8*)(tmp + 8);
    }
    if (t < 64) kml[t] = kmean[b * 256 + h * 64 + t];
    __syncthreads();

    {
        const unsigned short* qp = q_rope + (size_t)(b * 4096 + n0 + t) * 256 + h * 64;
        float q[64];
        #pragma unroll
        for (int u = 0; u < 8; ++u) {
            us8 v = *(const us8*)(qp + u * 8);
            #pragma unroll
            for (int j = 0; j < 8; ++j) q[u * 8 + j] = bf2f(v[j]);
        }
        int w = (n0 + t) & 63;
        float den = 0.f;
        #pragma unroll
        for (int j = 0; j < 32; ++j) {
            f2 cs = *(const f2*)(ropeT + (w * 128 + h * 32 + j) * 2);
            float kmx = kml[2 * j], kmy = kml[2 * j + 1];
            den += q[2 * j] * (cs[0] * kmx - cs[1] * kmy) + q[2 * j + 1] * (cs[1] * kmx + cs[0] * kmy);
        }
        zl[t] = 1.0f / (den + 1e-6f);
    }
    __syncthreads();

    s8 bfr[4][2];
    #pragma unroll
    for (int nt = 0; nt < 4; ++nt)
        #pragma unroll
        for (int ks = 0; ks < 2; ++ks)
            bfr[nt][ks] = *(const s8*)&kvB[(nt * 16 + mr) * 64 + ks * 32 + koff];

    const unsigned short* Ab = q_rope + (size_t)(b * 4096 + n0 + wv * 64) * 256 + h * 64;
    f4 acc[4][4];
    #pragma unroll
    for (int a = 0; a < 4; ++a)
        #pragma unroll
        for (int bn = 0; bn < 4; ++bn) { acc[a][bn][0]=0.f; acc[a][bn][1]=0.f; acc[a][bn][2]=0.f; acc[a][bn][3]=0.f; }

    #pragma unroll
    for (int ks = 0; ks < 2; ++ks) {
        s8 af[4];
        #pragma unroll
        for (int mt = 0; mt < 4; ++mt)
            af[mt] = *(const s8*)(Ab + (size_t)(mt * 16 + mr) * 256 + ks * 32 + koff);
        #pragma unroll
        for (int mt = 0; mt < 4; ++mt)
            #pragma unroll
            for (int nt = 0; nt < 4; ++nt)
                acc[mt][nt] = __builtin_amdgcn_mfma_f32_16x16x32_bf16(af[mt], bfr[nt][ks], acc[mt][nt], 0, 0, 0);
    }

    float* sw = trans[wv];
    for (int half = 0; half < 2; ++half) {
        #pragma unroll
        for (int mt2 = 0; mt2 < 2; ++mt2) {
            #pragma unroll
            for (int r = 0; r < 4; ++r) {
                int row_rel = mt2 * 16 + quad * 4 + r;
                float z = zl[wv * 64 + half * 32 + row_rel];
                #pragma unroll
                for (int nt = 0; nt < 4; ++nt)
                    sw[row_rel * 65 + nt * 16 + mr] = acc[half * 2 + mt2][nt][r] * z;
            }
        }
        __syncthreads();
        float tmp[32];
        #pragma unroll
        for (int i = 0; i < 32; ++i) tmp[i] = sw[i * 65 + lane];
        float* orow = out + (size_t)(b * 256 + h * 64 + lane) * 4096 + n0 + wv * 64 + half * 32;
        #pragma unroll
        for (int u = 0; u < 8; ++u)
            *(f4*)(orow + u * 4) = *(const f4*)(tmp + u * 4);
        __syncthreads();
    }
}

// ---------------------------------------------------------------------------
// K7: LePE 3x3 depthwise conv on v (bf16 [b,c,n]) + bias, RMW-add into d_out.
// grid (256 c, 16 b), block 256
// ---------------------------------------------------------------------------
__global__ __launch_bounds__(256) void k7_lepe(
    const unsigned short* __restrict__ vT, const float* __restrict__ lw,
    const float* __restrict__ lb, float* __restrict__ out)
{
    __shared__ float tile[66 * 68];
    const int t = threadIdx.x;
    const int c = blockIdx.x, b = blockIdx.y;
    const unsigned short* fc = vT + (size_t)(b * C_ + c) * N_;
    for (int i = 0; i < 18; ++i) {
        int flat = i * 256 + t;
        if (flat < 66 * 68) {
            int r = flat / 68, col = flat % 68;
            int h = r - 1, w = col - 1;
            float v = 0.f;
            if ((unsigned)h < 64u && (unsigned)w < 64u) v = bf2f(fc[h * 64 + w]);
            tile[r * 68 + col] = v;
        }
    }
    __syncthreads();
    float w00 = lw[c*9+0], w01 = lw[c*9+1], w02 = lw[c*9+2];
    float w10 = lw[c*9+3], w11 = lw[c*9+4], w12 = lw[c*9+5];
    float w20 = lw[c*9+6], w21 = lw[c*9+7], w22 = lw[c*9+8];
    float bias = lb[c];
    const int w4 = (t & 15) * 4;
    float* oc = out + (size_t)(b * C_ + c) * N_;
    for (int hh = 0; hh < 4; ++hh) {
        int h = (t >> 4) + hh * 16;
        float r0[6], r1[6], r2[6];
        #pragma unroll
        for (int u = 0; u < 6; ++u) {
            r0[u] = tile[(h + 0) * 68 + w4 + u];
            r1[u] = tile[(h + 1) * 68 + w4 + u];
            r2[u] = tile[(h + 2) * 68 + w4 + u];
        }
        f4 prev = *(const f4*)&oc[h * 64 + w4];
        #pragma unroll
        for (int j = 0; j < 4; ++j) {
            float o = bias;
            o = fmaf(w00, r0[j],   o); o = fmaf(w01, r0[j+1], o); o = fmaf(w02, r0[j+2], o);
            o = fmaf(w10, r1[j],   o); o = fmaf(w11, r1[j+1], o); o = fmaf(w12, r1[j+2], o);
            o = fmaf(w20, r2[j],   o); o = fmaf(w21, r2[j+1], o); o = fmaf(w22, r2[j+2], o);
            prev[j] += o;
        }
        *(f4*)&oc[h * 64 + w4] = prev;
    }
}

// ---------------------------------------------------------------------------
extern "C" void kernel_launch(void* const* d_in, const int* in_sizes, int n_in,
                              void* d_out, int out_size, void* d_ws, size_t ws_size,
                              hipStream_t stream)
{
    const float* x   = (const float*)d_in[0];
    const float* w3  = (const float*)d_in[1];  const float* b3 = (const float*)d_in[2];
    const float* w5  = (const float*)d_in[3];  const float* b5 = (const float*)d_in[4];
    const float* w7  = (const float*)d_in[5];  const float* b7 = (const float*)d_in[6];
    const float* w9  = (const float*)d_in[7];  const float* b9 = (const float*)d_in[8];
    const float* gnw = (const float*)d_in[9];  const float* gnb = (const float*)d_in[10];
    const float* fw  = (const float*)d_in[11];
    const float* qkw = (const float*)d_in[12];
    const float* lw  = (const float*)d_in[13]; const float* lb = (const float*)d_in[14];

    char* ws = (char*)d_ws;
    // layout (bytes):
    //   [0, 128MiB)     y bf16 [4][B][C][N]  -- ALIASED later by q_rope (0..32M)
    //                   and k_ropeT (32M..64M); y dead after k2.
    //   [128M, 160M)    xs bf16 [B][N][C]
    //   [160M, 192M)    vT bf16 [B][C][N]
    //   [192M, +256K)   qk_w bf16
    //   then stats (2KB) | kmean (16KB) | kv fp32 (1MB)  -- one memset
    //   then ropeT fp32 64KB (fully overwritten by k0, no memset)
    unsigned short* y      = (unsigned short*)(ws + 0);
    unsigned short* q_rope = (unsigned short*)(ws + 0);
    unsigned short* kT     = (unsigned short*)(ws + 33554432ull);
    unsigned short* xs     = (unsigned short*)(ws + 134217728ull);
    unsigned short* vT     = (unsigned short*)(ws + 167772160ull);
    unsigned short* wb     = (unsigned short*)(ws + 201326592ull);
    float*          stats  = (float*)(ws + 201588736ull);
    float*          kmean  = (float*)(ws + 201590784ull);
    float*          kv     = (float*)(ws + 201607168ull);
    float*          ropeT  = (float*)(ws + 202655744ull);

    (void)hipMemsetAsync(stats, 0, 2048 + 16384 + 1048576, stream);

    k0_rope<<<dim3(32), 256, 0, stream>>>(ropeT);
    k1_conv_stats<<<dim3(2, 256, 16), 256, 0, stream>>>(x, w3, b3, w5, b5, w7, b7, w9, b9, y, stats);
    k2b_cvt<<<dim3(512), 256, 0, stream>>>(qkw, wb, 131072);
    k2_fuse<<<dim3(64, 4, 16), 256, 0, stream>>>(y, stats, gnw, gnb, fw, xs, vT);
    k3_gemm<<<dim3(1024), 256, 0, stream>>>((const short*)xs, (const short*)wb, ropeT, q_rope, kT, kmean);
    k5_kv<<<dim3(16, 4, 16), 256, 0, stream>>>(kT, vT, kv);
    k6_attn<<<dim3(16, 4, 16), 256, 0, stream>>>(q_rope, kmean, kv, ropeT, (float*)d_out);
    k7_lepe<<<dim3(256, 16), 256, 0, stream>>>(vT, lw, lb, (float*)d_out);
}